// Round 13
// baseline (112.857 us; speedup 1.0000x reference)
//
#include <hip/hip_runtime.h>

// Batched MLP, round 13: r12's fully-rotated pipeline + 1-trans tanh.
// tanh = sign(z) * (1 - 2*t*r), t = exp2(-|z|), r = 1/(1+t) via quadratic
// seed + 1 Newton (d in (1,2], rel err ~1e-4; HW-validated in r8: absmax
// 0.5625). Halves trans-unit occupancy (the densest pipe in the interleaved
// structure: 2 trans/value -> 1) at the cost of ~4 extra full-rate VALU ops
// which the MFMA/LDS slots can host. Structure otherwise identical to r12.

#define IND      16
#define THREADS  1024
#define PARAMS   51841
#define SCALE    2.8853900817779268f   // 2*log2(e)

#define WS_W0    12582912                  // [0,WS_W0): 128*3 hidden W images
#define WS_SC    (WS_W0 + 128 * 8192)      // per-t W0 frag images (hi|lo)
#define WS_X     (WS_SC + 128 * 4096)      // per-t scalar blocks
#define WS_XLO   (WS_X + 131072)           // x hi rows then lo rows
#define WS_TOTAL (WS_X + 262144)           // 14,417,920

// per-t scalar block (f32): +0 b0s(128) | +128 b1..3s(384) | +512 wl(128) | +640 bl

#define LDS_B    98304                      // 3 W images below
#define LDS_WL   (LDS_B + 1536)
#define LDS_SZ   (LDS_B + 2064)

typedef _Float16 f16x8 __attribute__((ext_vector_type(8)));
typedef _Float16 f16x4 __attribute__((ext_vector_type(4)));
typedef float    f32x16 __attribute__((ext_vector_type(16)));
typedef float    f32x4v __attribute__((ext_vector_type(4)));
typedef float    f32x2v __attribute__((ext_vector_type(2)));
typedef unsigned u32x2  __attribute__((ext_vector_type(2)));

union U4 { unsigned u[4]; f16x8 v; };

// z PRE-SCALED by 2*log2(e). 1-trans tanh: t = 2^(-|z|) in (0,1],
// r = 1/(1+t) via quadratic seed + 1 Newton, y = sign(z)*(1 - 2*t*r).
// Saturates: |z| large -> t=0 -> y=+/-1. Validated r8 (absmax 0.5625).
__device__ __forceinline__ float tanh1(float z) {
    const float t = __builtin_amdgcn_exp2f(-__builtin_fabsf(z));
    const float d = t + 1.0f;
    float r = __builtin_fmaf(d, __builtin_fmaf(d, 0.32302f, -1.45380f), 2.12094f);
    r = __builtin_fmaf(r, __builtin_fmaf(-d, r, 1.0f), r);
    const float u = __builtin_fmaf(t * r, -2.0f, 1.0f);
    return __builtin_copysignf(u, z);
}
__device__ __forceinline__ unsigned tanh2pk(float z0, float z1) {
    return __builtin_bit_cast(unsigned,
        __builtin_amdgcn_cvt_pkrtz(tanh1(z0), tanh1(z1)));
}

#define MFMA(A, B, C) __builtin_amdgcn_mfma_f32_32x32x16_f16((A), (B), (C), 0, 0, 0)

__device__ __forceinline__ void gload16(const void* g, void* l) {
    __builtin_amdgcn_global_load_lds(
        (const __attribute__((address_space(1))) void*)g,
        (__attribute__((address_space(3))) void*)l, 16, 0, 0);
}

__device__ __forceinline__ void conv8(const float* __restrict__ s, char* hidst,
                                      char* lodst, float scale) {
    float v[8];
    *reinterpret_cast<float4*>(v)     = *reinterpret_cast<const float4*>(s);
    *reinterpret_cast<float4*>(v + 4) = *reinterpret_cast<const float4*>(s + 4);
    f16x8 hi, lo;
#pragma unroll
    for (int i = 0; i < 8; ++i) {
        const float sv = v[i] * scale;
        hi[i] = (_Float16)sv;
        lo[i] = (_Float16)(sv - (float)hi[i]);
    }
    *reinterpret_cast<f16x8*>(hidst) = hi;
    *reinterpret_cast<f16x8*>(lodst) = lo;
}

// ---------------------------------------------------------------------------
// prep (identical to rounds 10-12)
// ---------------------------------------------------------------------------
__global__ __launch_bounds__(256)
void prep_kernel(const float* __restrict__ theta, const float* __restrict__ xin,
                 char* __restrict__ ws)
{
    const int b = blockIdx.x, tid = threadIdx.x;
    if (b < 3072) {
        const int t = b / 24, rem = b % 24, li = rem >> 3, hblk = rem & 7;
        const int h  = hblk * 16 + (tid >> 4);
        const int kc = (tid >> 1) & 7, kh = tid & 1;
        const float* src = theta + (size_t)t * PARAMS + 2176 + li * 16512
                         + h * 128 + kc * 16 + kh * 8;
        float v[8];
        *reinterpret_cast<float4*>(v)     = *reinterpret_cast<const float4*>(src);
        *reinterpret_cast<float4*>(v + 4) = *reinterpret_cast<const float4*>(src + 4);
        f16x8 p;
#pragma unroll
        for (int i = 0; i < 8; ++i) p[i] = (_Float16)(v[i] * SCALE);
        char* img = ws + ((size_t)(t * 3 + li) << 15);
        *reinterpret_cast<f16x8*>(img + ((h >> 5) * 8 + kc) * 1024
                                      + (kh * 32 + (h & 31)) * 16) = p;
    } else if (b < 3136) {
        const int gid = (b - 3072) * 256 + tid;
        const int t = gid >> 7, h = gid & 127;
        const float* src = theta + (size_t)t * PARAMS + h * IND;
        char* dst = ws + WS_W0 + (size_t)t * 8192 + h * 32;
        conv8(src,     dst,      dst + 4096,      SCALE);
        conv8(src + 8, dst + 16, dst + 4096 + 16, SCALE);
    } else if (b < 3264) {
        const int t = b - 3136;
        const float* th = theta + (size_t)t * PARAMS;
        float* base = reinterpret_cast<float*>(ws + WS_SC + (size_t)t * 4096);
        if (tid < 128) base[tid] = SCALE * th[2048 + tid];                 // b0s
        for (int k = tid; k < 384; k += 256)                               // b1..3s
            base[128 + k] = SCALE * th[2176 + (k >> 7) * 16512 + 16384 + (k & 127)];
        if (tid < 128) base[512 + tid] = th[51712 + tid];                  // wl
        if (tid == 0)  base[640] = th[51840];                              // bl
    } else {
        const int row = (b - 3264) * 256 + tid;
        const float* src = xin + (size_t)row * IND;
        char* hid = ws + WS_X   + (size_t)row * 32;
        char* lod = ws + WS_XLO + (size_t)row * 32;
        conv8(src,     hid,      lod,      1.0f);
        conv8(src + 8, hid + 16, lod + 16, 1.0f);
    }
}

// ---------------------------------------------------------------------------
// main: 1024 threads (16 waves, 4/SIMD), 1 block/CU, ONE barrier,
// fully-rotated pack pipeline + 1-trans tanh.
// ---------------------------------------------------------------------------
__global__ __launch_bounds__(THREADS, 4)
void mlp_main(const char* __restrict__ ws, float* __restrict__ out)
{
    __shared__ __align__(16) char sL[LDS_SZ];

    const int tid = threadIdx.x, bid = blockIdx.x;
    const int sw  = (bid & 7) * 128 + (bid >> 3);   // XCD-bijective (1024%8==0)
    const int t   = sw >> 3, xt = sw & 7;           // xt: 512-x tile index
    const int lane = tid & 63, w = tid >> 6, r31 = lane & 31, khalf = lane >> 5;
    const int bpa  = (lane ^ 32) << 2;
    (void)bpa;

    const float* __restrict__ wsc = reinterpret_cast<const float*>(
        ws + WS_SC + (size_t)t * 4096);

    // ---- issue stage of W1|W2|W3 (96KB contiguous) -> LDS[0,96K) ----
    {
        const char* img = ws + ((size_t)(t * 3) << 15);
#pragma unroll
        for (int c = 0; c < 6; ++c) {
            const int o = (c * 1024 + tid) * 16;
            gload16(img + o, sL + o);
        }
    }
    // ---- stage scaled b1..3 + wl + bl tables ----
    if (tid < 513)
        *reinterpret_cast<float*>(sL + LDS_B + tid * 4) = wsc[128 + tid];

    // ------------------------ helpers ------------------------
    auto asm2 = [&](const unsigned* P0, const unsigned* P1, f16x8* dst) {
#pragma unroll
        for (int j = 0; j < 2; ++j) {
#if __has_builtin(__builtin_amdgcn_permlane32_swap)
            const u32x2 r0 = __builtin_amdgcn_permlane32_swap(
                P0[2 * j], P0[2 * j + 1], false, false);
            const u32x2 r1 = __builtin_amdgcn_permlane32_swap(
                P1[2 * j], P1[2 * j + 1], false, false);
            U4 u;
            u.u[0] = r0[0]; u.u[1] = r1[0]; u.u[2] = r0[1]; u.u[3] = r1[1];
#else
            const unsigned s0 = khalf ? P0[2 * j] : P0[2 * j + 1];
            const unsigned s1 = khalf ? P1[2 * j] : P1[2 * j + 1];
            const unsigned q0 = (unsigned)__builtin_amdgcn_ds_bpermute(bpa, (int)s0);
            const unsigned q1 = (unsigned)__builtin_amdgcn_ds_bpermute(bpa, (int)s1);
            U4 u;
            u.u[0] = khalf ? q0 : P0[2 * j];
            u.u[1] = khalf ? q1 : P1[2 * j];
            u.u[2] = khalf ? P0[2 * j + 1] : q0;
            u.u[3] = khalf ? P1[2 * j + 1] : q1;
#endif
            dst[j] = u.v;
        }
    };
    auto pack2 = [&](const f32x16& a, f16x8* dst) {   // serial pack (prologue)
        unsigned P0[4], P1[4];
#pragma unroll
        for (int g = 0; g < 4; ++g) {
            P0[g] = tanh2pk(a[4 * g + 0], a[4 * g + 1]);
            P1[g] = tanh2pk(a[4 * g + 2], a[4 * g + 3]);
        }
        asm2(P0, P1, dst);
    };
    auto biasin = [&](f32x16& a, const char* btab, int tt) {
#pragma unroll
        for (int g = 0; g < 4; ++g) {
            const f32x4v bv = *reinterpret_cast<const f32x4v*>(
                btab + (tt * 32 + g * 8) * 4 + khalf * 16);
            a[4 * g + 0] = bv[0]; a[4 * g + 1] = bv[1];
            a[4 * g + 2] = bv[2]; a[4 * g + 3] = bv[3];
        }
    };
    // tile0 of a layer: MFMAs kc0..7 using frags G; interleaves pack(src) whose
    // output IS G[6],G[7] (asm2 lands before the kc6 MFMA that consumes it).
    auto tile0p = [&](f32x16& a, const char* wimg, f16x8* G, const f32x16& src) {
        unsigned P0[4], P1[4];
#pragma unroll
        for (int kc = 0; kc < 4; ++kc) {
            const f16x8 av = *reinterpret_cast<const f16x8*>(
                wimg + kc * 1024 + lane * 16);
            a = MFMA(av, G[kc], a);
            P0[kc] = tanh2pk(src[4 * kc + 0], src[4 * kc + 1]);
            P1[kc] = tanh2pk(src[4 * kc + 2], src[4 * kc + 3]);
        }
        {
            const f16x8 a4 = *reinterpret_cast<const f16x8*>(wimg + 4 * 1024 + lane * 16);
            a = MFMA(a4, G[4], a);
            const f16x8 a5 = *reinterpret_cast<const f16x8*>(wimg + 5 * 1024 + lane * 16);
            a = MFMA(a5, G[5], a);
        }
        asm2(P0, P1, G + 6);
        {
            const f16x8 a6 = *reinterpret_cast<const f16x8*>(wimg + 6 * 1024 + lane * 16);
            a = MFMA(a6, G[6], a);
            const f16x8 a7 = *reinterpret_cast<const f16x8*>(wimg + 7 * 1024 + lane * 16);
            a = MFMA(a7, G[7], a);
        }
    };
    // tiles 1..3: MFMAs kc0..7 ∥ pack(src) -> dst2 (next-layer frags)
    auto inter8p = [&](f32x16& a, const char* wimg, int tt, const f16x8* G,
                       const f32x16& src, f16x8* dst2) {
        unsigned P0[4], P1[4];
#pragma unroll
        for (int kc = 0; kc < 8; ++kc) {
            const f16x8 av = *reinterpret_cast<const f16x8*>(
                wimg + (tt * 8 + kc) * 1024 + lane * 16);
            a = MFMA(av, G[kc], a);
            const int g = kc >> 1;
            if (!(kc & 1)) P0[g] = tanh2pk(src[4 * g + 0], src[4 * g + 1]);
            else           P1[g] = tanh2pk(src[4 * g + 2], src[4 * g + 3]);
        }
        asm2(P0, P1, dst2);
    };
    // final-layer tiles 1..3: MFMAs ∥ dot-slice of src (tile tts) into s
    auto inter8d = [&](f32x16& a, const char* wimg, int tt, const f16x8* G,
                       const f32x16& src, int tts, float& s) {
#pragma unroll
        for (int kc = 0; kc < 8; ++kc) {
            const f16x8 av = *reinterpret_cast<const f16x8*>(
                wimg + (tt * 8 + kc) * 1024 + lane * 16);
            a = MFMA(av, G[kc], a);
            const int j = 2 * kc;                 // values j, j+1 (same g)
            const int g = j >> 2, q = j & 3;
            const f32x2v wv = *reinterpret_cast<const f32x2v*>(
                sL + LDS_WL + (tts * 32 + g * 8 + khalf * 4 + q) * 4);
            s = __builtin_fmaf(tanh1(src[j]),     wv[0], s);
            s = __builtin_fmaf(tanh1(src[j + 1]), wv[1], s);
        }
    };
    auto fdot = [&](const f32x16& a, int tt, float& s) {  // serial (epilogue)
#pragma unroll
        for (int g = 0; g < 4; ++g) {
            const f32x4v wv = *reinterpret_cast<const f32x4v*>(
                sL + LDS_WL + (tt * 32 + g * 8) * 4 + khalf * 16);
#pragma unroll
            for (int q = 0; q < 4; ++q)
                s = __builtin_fmaf(tanh1(a[4 * g + q]), wv[q], s);
        }
    };

    // ------------------------ layer 0 (prologue) --------------------------
    f16x8 G[8], N[8];
    f32x16 pc;                                  // carried unpacked accumulator
    {
        const char* w0i = ws + WS_W0 + (size_t)t * 8192;
        const int ro = r31 * 32 + khalf * 16;
        const int xrow = (xt * 512 + w * 32) * 32;
        const f16x8 B0h = *reinterpret_cast<const f16x8*>(ws + WS_X   + xrow + ro);
        const f16x8 B0l = *reinterpret_cast<const f16x8*>(ws + WS_XLO + xrow + ro);
        auto l0tile = [&](f32x16& a, int tt) {
#pragma unroll
            for (int g = 0; g < 4; ++g) {
                const f32x4v bv = *reinterpret_cast<const f32x4v*>(
                    wsc + tt * 32 + g * 8 + khalf * 4);
                a[4 * g + 0] = bv[0]; a[4 * g + 1] = bv[1];
                a[4 * g + 2] = bv[2]; a[4 * g + 3] = bv[3];
            }
            const f16x8 Ah = *reinterpret_cast<const f16x8*>(w0i + tt * 1024 + ro);
            const f16x8 Al = *reinterpret_cast<const f16x8*>(w0i + 4096 + tt * 1024 + ro);
            a = MFMA(Al, B0h, a);
            a = MFMA(Ah, B0l, a);
            a = MFMA(Ah, B0h, a);
        };
        f32x16 c0, c1;
        l0tile(c0, 0); l0tile(c1, 1);
        pack2(c0, G + 0); pack2(c1, G + 2);
        l0tile(c0, 2); l0tile(pc, 3);
        pack2(c0, G + 4);                       // pc (= layer0 c3) stays unpacked
    }
    __syncthreads();   // THE ONLY BARRIER: W1..W3 + tables visible

    // ------------------------ hidden layer (rotated pipeline) -------------
    auto hidden = [&](const char* wimg, const char* btab,
                      f16x8* Gc, f16x8* Nn) {
        f32x16 c0, c1, c2, c3;
        __builtin_amdgcn_s_setprio(1);
        biasin(c0, btab, 0); tile0p(c0, wimg, Gc, pc);        // ∥ pack(prev c3)
        biasin(c1, btab, 1); inter8p(c1, wimg, 1, Gc, c0, Nn + 0);
        biasin(c2, btab, 2); inter8p(c2, wimg, 2, Gc, c1, Nn + 2);
        biasin(c3, btab, 3); inter8p(c3, wimg, 3, Gc, c2, Nn + 4);
        __builtin_amdgcn_s_setprio(0);
        pc = c3;                                              // carried unpacked
    };

    hidden(sL,         sL + LDS_B,       G, N);   // W1: cur=G, next=N
    hidden(sL + 32768, sL + LDS_B + 512, N, G);   // W2: cur=N, next=G

    // ------------------------ final layer (W3 + wl dot) -------------------
    float s = 0.0f;
    {
        const char* wimg = sL + 65536;
        const char* btab = sL + LDS_B + 1024;
        f32x16 c0f, c1f, c2f, c3f;
        __builtin_amdgcn_s_setprio(1);
        biasin(c0f, btab, 0); tile0p(c0f, wimg, G, pc);       // ∥ pack(W2's c3)
        biasin(c1f, btab, 1); inter8d(c1f, wimg, 1, G, c0f, 0, s);
        biasin(c2f, btab, 2); inter8d(c2f, wimg, 2, G, c1f, 1, s);
        biasin(c3f, btab, 3); inter8d(c3f, wimg, 3, G, c2f, 2, s);
        __builtin_amdgcn_s_setprio(0);
        fdot(c3f, 3, s);
    }
    const float sp = __builtin_bit_cast(float,
        __builtin_amdgcn_ds_bpermute(bpa, __builtin_bit_cast(int, s)));
    const float res = s + sp + *reinterpret_cast<const float*>(sL + LDS_WL + 512);
    if (!khalf) out[(size_t)t * 4096 + xt * 512 + w * 32 + r31] = res;
}

// ---------------------------------------------------------------------------
// Fallback (self-contained, known-good round-1 kernel) if ws is too small.
// ---------------------------------------------------------------------------
__global__ __launch_bounds__(256, 1)
void mlp_kernel_fb(const float* __restrict__ xin,
                   const float* __restrict__ theta,
                   float* __restrict__ out)
{
    __shared__ __align__(16) _Float16 sH   [128 * 128];
    __shared__ __align__(16) _Float16 sWhi [128 * 128];
    __shared__ __align__(16) _Float16 sWlo [128 * 128];
    __shared__ __align__(16) _Float16 sX0hi[128 * IND];
    __shared__ __align__(16) _Float16 sX0lo[128 * IND];
    __shared__ __align__(16) _Float16 sW0hi[128 * IND];
    __shared__ __align__(16) _Float16 sW0lo[128 * IND];
    __shared__ float sB[2][128];
    __shared__ float sWl[129];

    const int tid = threadIdx.x;
    const int bid = blockIdx.x;
    const int sw  = (bid & 7) * 512 + (bid >> 3);
    const int t   = sw >> 5;
    const int xt  = sw & 31;
    const float* __restrict__ th = theta + (size_t)t * PARAMS;
    const float* __restrict__ xg = xin   + (size_t)xt * (128 * IND);

#pragma unroll
    for (int j = 0; j < 2; ++j) {
        const int flat = j * 1024 + tid * 4;
        const float4 v = *reinterpret_cast<const float4*>(xg + flat);
        _Float16 h0 = (_Float16)v.x, h1 = (_Float16)v.y, h2 = (_Float16)v.z, h3 = (_Float16)v.w;
        f16x4 ph = {h0, h1, h2, h3};
        f16x4 pl = {(_Float16)(v.x - (float)h0), (_Float16)(v.y - (float)h1),
                    (_Float16)(v.z - (float)h2), (_Float16)(v.w - (float)h3)};
        *reinterpret_cast<f16x4*>(&sX0hi[flat]) = ph;
        *reinterpret_cast<f16x4*>(&sX0lo[flat]) = pl;
    }
#pragma unroll
    for (int j = 0; j < 2; ++j) {
        const int flat = j * 1024 + tid * 4;
        const float a0 = th[flat], a1 = th[flat + 1], a2 = th[flat + 2], a3 = th[flat + 3];
        _Float16 h0 = (_Float16)a0, h1 = (_Float16)a1, h2 = (_Float16)a2, h3 = (_Float16)a3;
        f16x4 ph = {h0, h1, h2, h3};
        f16x4 pl = {(_Float16)(a0 - (float)h0), (_Float16)(a1 - (float)h1),
                    (_Float16)(a2 - (float)h2), (_Float16)(a3 - (float)h3)};
        *reinterpret_cast<f16x4*>(&sW0hi[flat]) = ph;
        *reinterpret_cast<f16x4*>(&sW0lo[flat]) = pl;
    }
    if (tid < 128) sB[0][tid] = th[IND * 128 + tid];
    __syncthreads();

    const int lane  = tid & 63;
    const int w     = tid >> 6;
    const int r31   = lane & 31;
    const int khalf = lane >> 5;
    const int hb    = (w >> 1) * 64;
    const int xb    = (w & 1) * 64;
    const int hA0 = hb + r31,  hA1 = hb + 32 + r31;
    const int xB0 = xb + r31,  xB1 = xb + 32 + r31;
    const int swzA0 = (hA0 & 15) << 4, swzA1 = (hA1 & 15) << 4;
    const int swzB0 = (xB0 & 15) << 4, swzB1 = (xB1 & 15) << 4;

    f32x16 acc[2][2];

    {
        const int kb = khalf * 16;
        f16x8 ah[2], al[2], bh[2], bl[2];
        ah[0] = *reinterpret_cast<const f16x8*>((const char*)sW0hi + hA0 * 32 + kb);
        ah[1] = *reinterpret_cast<const f16x8*>((const char*)sW0hi + hA1 * 32 + kb);
        al[0] = *reinterpret_cast<const f16x8*>((const char*)sW0lo + hA0 * 32 + kb);
        al[1] = *reinterpret_cast<const f16x8*>((const char*)sW0lo + hA1 * 32 + kb);
        bh[0] = *reinterpret_cast<const f16x8*>((const char*)sX0hi + xB0 * 32 + kb);
        bh[1] = *reinterpret_cast<const f16x8*>((const char*)sX0hi + xB1 * 32 + kb);
        bl[0] = *reinterpret_cast<const f16x8*>((const char*)sX0lo + xB0 * 32 + kb);
        bl[1] = *reinterpret_cast<const f16x8*>((const char*)sX0lo + xB1 * 32 + kb);
#pragma unroll
        for (int tt = 0; tt < 2; ++tt)
#pragma unroll
            for (int tx = 0; tx < 2; ++tx) {
                f32x16 a;
#pragma unroll
                for (int i = 0; i < 16; ++i) a[i] = 0.0f;
                a = MFMA(al[tt], bh[tx], a);
                a = MFMA(ah[tt], bl[tx], a);
                a = MFMA(ah[tt], bh[tx], a);
                acc[tt][tx] = a;
            }
    }

    auto epilogue = [&](const float* __restrict__ bb) {
#pragma unroll
        for (int tt = 0; tt < 2; ++tt)
#pragma unroll
            for (int tx = 0; tx < 2; ++tx) {
                const int xw  = xb + tx * 32 + r31;
                const int swz = (xw & 15) << 4;
#pragma unroll
                for (int g = 0; g < 4; ++g) {
                    const int hbase = hb + tt * 32 + g * 8 + khalf * 4;
                    f16x4 pk;
#pragma unroll
                    for (int q = 0; q < 4; ++q) {
                        const float v = acc[tt][tx][g * 4 + q] + bb[hbase + q];
                        pk[q] = (_Float16)(1.0f - 2.0f * __builtin_amdgcn_rcpf(
                            __builtin_amdgcn_exp2f(v * 2.8853900817779268f) + 1.0f));
                    }
                    *reinterpret_cast<f16x4*>((char*)sH + xw * 256 + ((hbase * 2) ^ swz)) = pk;
                }
            }
    };

    for (int l = 0; l < 3; ++l) {
        __syncthreads();
        const float* __restrict__ wsrc = th + 2176 + l * 16512;
#pragma unroll
        for (int j = 0; j < 16; ++j) {
            const int flat = j * 1024 + tid * 4;
            const int hrow = flat >> 7;
            const int o    = flat & 127;
            const float a0 = wsrc[flat], a1 = wsrc[flat + 1], a2 = wsrc[flat + 2], a3 = wsrc[flat + 3];
            _Float16 h0 = (_Float16)a0, h1 = (_Float16)a1, h2 = (_Float16)a2, h3 = (_Float16)a3;
            f16x4 ph = {h0, h1, h2, h3};
            f16x4 pl = {(_Float16)(a0 - (float)h0), (_Float16)(a1 - (float)h1),
                        (_Float16)(a2 - (float)h2), (_Float16)(a3 - (float)h3)};
            const int boff = hrow * 256 + ((o * 2) ^ ((hrow & 15) << 4));
            *reinterpret_cast<f16x4*>((char*)sWhi + boff) = ph;
            *reinterpret_cast<f16x4*>((char*)sWlo + boff) = pl;
        }
        if (tid < 128) sB[(l + 1) & 1][tid] = wsrc[128 * 128 + tid];
        if (l == 2) {
            if (tid < 128) sWl[tid] = th[51712 + tid];
            if (tid == 128) sWl[128] = th[51840];
        }

        epilogue(sB[l & 1]);
        __syncthreads();

#pragma unroll
        for (int tt = 0; tt < 2; ++tt)
#pragma unroll
            for (int tx = 0; tx < 2; ++tx)
#pragma unroll
                for (int i = 0; i < 16; ++i) acc[tt][tx][i] = 0.0f;
#pragma unroll
        for (int kc = 0; kc < 8; ++kc) {
            const int kb = kc * 32 + khalf * 16;
            f16x8 ah[2], al[2], bv[2];
            ah[0] = *reinterpret_cast<const f16x8*>((const char*)sWhi + hA0 * 256 + (kb ^ swzA0));
            ah[1] = *reinterpret_cast<const f16x8*>((const char*)sWhi + hA1 * 256 + (kb ^ swzA1));
            al[0] = *reinterpret_cast<const f16x8*>((const char*)sWlo + hA0 * 256 + (kb ^ swzA0));
            al[1] = *reinterpret_cast<const f16x8*>((const char*)sWlo + hA1 * 256 + (kb ^ swzA1));
            bv[0] = *reinterpret_cast<const f16x8*>((const char*)sH   + xB0 * 256 + (kb ^ swzB0));
            bv[1] = *reinterpret_cast<const f16x8*>((const char*)sH   + xB1 * 256 + (kb ^ swzB1));
#pragma unroll
            for (int tt = 0; tt < 2; ++tt)
#pragma unroll
                for (int tx = 0; tx < 2; ++tx) {
                    acc[tt][tx] = MFMA(al[tt], bv[tx], acc[tt][tx]);
                    acc[tt][tx] = MFMA(ah[tt], bv[tx], acc[tt][tx]);
                }
        }
    }

    __syncthreads();
    epilogue(sB[1]);
    __syncthreads();

    if (tid < 128) {
        const int r   = tid;
        const int swz = (r & 15) << 4;
        float s = 0.0f;
#pragma unroll
        for (int c = 0; c < 16; ++c) {
            const int hc = (c + r) & 15;
            const f16x8 hv = *reinterpret_cast<const f16x8*>(
                (const char*)sH + r * 256 + ((hc * 16) ^ swz));
#pragma unroll
            for (int q = 0; q < 8; ++q) s += (float)hv[q] * sWl[hc * 8 + q];
        }
        out[(size_t)t * 4096 + (size_t)xt * 128 + r] = s + sWl[128];
    }
}

extern "C" void kernel_launch(void* const* d_in, const int* in_sizes, int n_in,
                              void* d_out, int out_size, void* d_ws, size_t ws_size,
                              hipStream_t stream)
{
    const float* x     = (const float*)d_in[0];
    const float* theta = (const float*)d_in[1];
    float* out = (float*)d_out;

    if (ws_size >= (size_t)WS_TOTAL) {
        prep_kernel<<<dim3(3280), dim3(256), 0, stream>>>(theta, x, (char*)d_ws);
        mlp_main<<<dim3(1024), dim3(THREADS), 0, stream>>>((const char*)d_ws, out);
    } else {
        mlp_kernel_fb<<<dim3(4096), dim3(256), 0, stream>>>(x, theta, out);
    }
}

// Round 14
// 91.843 us; speedup vs baseline: 1.2288x; 1.2288x over previous
//
#include <hip/hip_runtime.h>

// Batched MLP, round 14: REVERT to round-11 (best measured: 91.69 us).
// 2-tile group pipeline: each layer = group0 (tiles 0,1) then group1 (tiles
// 2,3) whose MFMAs are interleaved in program order with the tanh+pack of
// group0, so one in-order wave feeds VALU(trans) and MFMA/LDS pipes
// simultaneously. 16 waves/CU, ONE barrier, 96KB persistent W in LDS.
// Numerics (absmax 0.578125): prescaled W/b (2*log2e), hi/lo layer 0, f16
// hidden W, tanh = 1 - 2*rcp(1+exp2(z)) (minimum-instruction form), RTZ pack.

#define IND      16
#define THREADS  1024
#define PARAMS   51841
#define SCALE    2.8853900817779268f   // 2*log2(e)

#define WS_W0    12582912                  // [0,WS_W0): 128*3 hidden W images
#define WS_SC    (WS_W0 + 128 * 8192)      // per-t W0 frag images (hi|lo)
#define WS_X     (WS_SC + 128 * 4096)      // per-t scalar blocks
#define WS_XLO   (WS_X + 131072)           // x hi rows then lo rows
#define WS_TOTAL (WS_X + 262144)           // 14,417,920

// per-t scalar block (f32): +0 b0s(128) | +128 b1..3s(384) | +512 wl(128) | +640 bl

#define LDS_B    98304                      // 3 W images below
#define LDS_WL   (LDS_B + 1536)
#define LDS_SZ   (LDS_B + 2064)

typedef _Float16 f16x8 __attribute__((ext_vector_type(8)));
typedef _Float16 f16x4 __attribute__((ext_vector_type(4)));
typedef float    f32x16 __attribute__((ext_vector_type(16)));
typedef float    f32x4v __attribute__((ext_vector_type(4)));
typedef unsigned u32x2  __attribute__((ext_vector_type(2)));

union U4 { unsigned u[4]; f16x8 v; };

// z PRE-SCALED by 2*log2(e): tanh = 1 - 2*rcp(1 + exp2(z)); saturates right.
__device__ __forceinline__ unsigned tanh2pk(float z0, float z1) {
    const float e0 = __builtin_amdgcn_exp2f(z0);
    const float e1 = __builtin_amdgcn_exp2f(z1);
    const float y0 = __builtin_fmaf(__builtin_amdgcn_rcpf(1.0f + e0), -2.0f, 1.0f);
    const float y1 = __builtin_fmaf(__builtin_amdgcn_rcpf(1.0f + e1), -2.0f, 1.0f);
    return __builtin_bit_cast(unsigned, __builtin_amdgcn_cvt_pkrtz(y0, y1));
}

#define MFMA(A, B, C) __builtin_amdgcn_mfma_f32_32x32x16_f16((A), (B), (C), 0, 0, 0)

__device__ __forceinline__ void gload16(const void* g, void* l) {
    __builtin_amdgcn_global_load_lds(
        (const __attribute__((address_space(1))) void*)g,
        (__attribute__((address_space(3))) void*)l, 16, 0, 0);
}

__device__ __forceinline__ void conv8(const float* __restrict__ s, char* hidst,
                                      char* lodst, float scale) {
    float v[8];
    *reinterpret_cast<float4*>(v)     = *reinterpret_cast<const float4*>(s);
    *reinterpret_cast<float4*>(v + 4) = *reinterpret_cast<const float4*>(s + 4);
    f16x8 hi, lo;
#pragma unroll
    for (int i = 0; i < 8; ++i) {
        const float sv = v[i] * scale;
        hi[i] = (_Float16)sv;
        lo[i] = (_Float16)(sv - (float)hi[i]);
    }
    *reinterpret_cast<f16x8*>(hidst) = hi;
    *reinterpret_cast<f16x8*>(lodst) = lo;
}

// ---------------------------------------------------------------------------
// prep (identical to round 10)
// ---------------------------------------------------------------------------
__global__ __launch_bounds__(256)
void prep_kernel(const float* __restrict__ theta, const float* __restrict__ xin,
                 char* __restrict__ ws)
{
    const int b = blockIdx.x, tid = threadIdx.x;
    if (b < 3072) {
        const int t = b / 24, rem = b % 24, li = rem >> 3, hblk = rem & 7;
        const int h  = hblk * 16 + (tid >> 4);
        const int kc = (tid >> 1) & 7, kh = tid & 1;
        const float* src = theta + (size_t)t * PARAMS + 2176 + li * 16512
                         + h * 128 + kc * 16 + kh * 8;
        float v[8];
        *reinterpret_cast<float4*>(v)     = *reinterpret_cast<const float4*>(src);
        *reinterpret_cast<float4*>(v + 4) = *reinterpret_cast<const float4*>(src + 4);
        f16x8 p;
#pragma unroll
        for (int i = 0; i < 8; ++i) p[i] = (_Float16)(v[i] * SCALE);
        char* img = ws + ((size_t)(t * 3 + li) << 15);
        *reinterpret_cast<f16x8*>(img + ((h >> 5) * 8 + kc) * 1024
                                      + (kh * 32 + (h & 31)) * 16) = p;
    } else if (b < 3136) {
        const int gid = (b - 3072) * 256 + tid;
        const int t = gid >> 7, h = gid & 127;
        const float* src = theta + (size_t)t * PARAMS + h * IND;
        char* dst = ws + WS_W0 + (size_t)t * 8192 + h * 32;
        conv8(src,     dst,      dst + 4096,      SCALE);
        conv8(src + 8, dst + 16, dst + 4096 + 16, SCALE);
    } else if (b < 3264) {
        const int t = b - 3136;
        const float* th = theta + (size_t)t * PARAMS;
        float* base = reinterpret_cast<float*>(ws + WS_SC + (size_t)t * 4096);
        if (tid < 128) base[tid] = SCALE * th[2048 + tid];                 // b0s
        for (int k = tid; k < 384; k += 256)                               // b1..3s
            base[128 + k] = SCALE * th[2176 + (k >> 7) * 16512 + 16384 + (k & 127)];
        if (tid < 128) base[512 + tid] = th[51712 + tid];                  // wl
        if (tid == 0)  base[640] = th[51840];                              // bl
    } else {
        const int row = (b - 3264) * 256 + tid;
        const float* src = xin + (size_t)row * IND;
        char* hid = ws + WS_X   + (size_t)row * 32;
        char* lod = ws + WS_XLO + (size_t)row * 32;
        conv8(src,     hid,      lod,      1.0f);
        conv8(src + 8, hid + 16, lod + 16, 1.0f);
    }
}

// ---------------------------------------------------------------------------
// main: 1024 threads (16 waves, 4/SIMD), 1 block/CU, ONE barrier,
// 2-tile-group software pipeline inside each layer.  (= round 11)
// ---------------------------------------------------------------------------
__global__ __launch_bounds__(THREADS, 4)
void mlp_main(const char* __restrict__ ws, float* __restrict__ out)
{
    __shared__ __align__(16) char sL[LDS_SZ];

    const int tid = threadIdx.x, bid = blockIdx.x;
    const int sw  = (bid & 7) * 128 + (bid >> 3);   // XCD-bijective (1024%8==0)
    const int t   = sw >> 3, xt = sw & 7;           // xt: 512-x tile index
    const int lane = tid & 63, w = tid >> 6, r31 = lane & 31, khalf = lane >> 5;
    const int bpa  = (lane ^ 32) << 2;
    (void)bpa;

    const float* __restrict__ wsc = reinterpret_cast<const float*>(
        ws + WS_SC + (size_t)t * 4096);

    // ---- issue stage of W1|W2|W3 (96KB contiguous) -> LDS[0,96K) ----
    {
        const char* img = ws + ((size_t)(t * 3) << 15);
#pragma unroll
        for (int c = 0; c < 6; ++c) {
            const int o = (c * 1024 + tid) * 16;
            gload16(img + o, sL + o);
        }
    }
    // ---- stage scaled b1..3 + wl + bl tables ----
    if (tid < 513)
        *reinterpret_cast<float*>(sL + LDS_B + tid * 4) = wsc[128 + tid];

    // ------------------------ helpers ------------------------
    auto asm2 = [&](const unsigned* P0, const unsigned* P1, f16x8* dst) {
#pragma unroll
        for (int j = 0; j < 2; ++j) {
#if __has_builtin(__builtin_amdgcn_permlane32_swap)
            const u32x2 r0 = __builtin_amdgcn_permlane32_swap(
                P0[2 * j], P0[2 * j + 1], false, false);
            const u32x2 r1 = __builtin_amdgcn_permlane32_swap(
                P1[2 * j], P1[2 * j + 1], false, false);
            U4 u;
            u.u[0] = r0[0]; u.u[1] = r1[0]; u.u[2] = r0[1]; u.u[3] = r1[1];
#else
            const unsigned s0 = khalf ? P0[2 * j] : P0[2 * j + 1];
            const unsigned s1 = khalf ? P1[2 * j] : P1[2 * j + 1];
            const unsigned q0 = (unsigned)__builtin_amdgcn_ds_bpermute(bpa, (int)s0);
            const unsigned q1 = (unsigned)__builtin_amdgcn_ds_bpermute(bpa, (int)s1);
            U4 u;
            u.u[0] = khalf ? q0 : P0[2 * j];
            u.u[1] = khalf ? q1 : P1[2 * j];
            u.u[2] = khalf ? P0[2 * j + 1] : q0;
            u.u[3] = khalf ? P1[2 * j + 1] : q1;
#endif
            dst[j] = u.v;
        }
    };
    auto pack2 = [&](const f32x16& a, f16x8* dst) {   // full pack of one tile
        unsigned P0[4], P1[4];
#pragma unroll
        for (int g = 0; g < 4; ++g) {
            P0[g] = tanh2pk(a[4 * g + 0], a[4 * g + 1]);
            P1[g] = tanh2pk(a[4 * g + 2], a[4 * g + 3]);
        }
        asm2(P0, P1, dst);
    };
    auto biasin = [&](f32x16& a, const char* btab, int tt) {
#pragma unroll
        for (int g = 0; g < 4; ++g) {
            const f32x4v bv = *reinterpret_cast<const f32x4v*>(
                btab + (tt * 32 + g * 8) * 4 + khalf * 16);
            a[4 * g + 0] = bv[0]; a[4 * g + 1] = bv[1];
            a[4 * g + 2] = bv[2]; a[4 * g + 3] = bv[3];
        }
    };
    auto mfma8 = [&](f32x16& a, const char* wimg, int tt,
                     const f16x8* in0, const f16x8* in1) {
#pragma unroll
        for (int kc = 0; kc < 8; ++kc) {
            const f16x8 av = *reinterpret_cast<const f16x8*>(
                wimg + (tt * 8 + kc) * 1024 + lane * 16);
            a = MFMA(av, kc < 4 ? in0[kc] : in1[kc - 4], a);
        }
    };
    // tile-tt MFMAs interleaved (program order!) with tanh of src -> P arrays
    auto inter8 = [&](f32x16& a, const char* wimg, int tt,
                      const f16x8* in0, const f16x8* in1,
                      const f32x16& src, unsigned* P0, unsigned* P1) {
#pragma unroll
        for (int kc = 0; kc < 8; ++kc) {
            const f16x8 av = *reinterpret_cast<const f16x8*>(
                wimg + (tt * 8 + kc) * 1024 + lane * 16);
            a = MFMA(av, kc < 4 ? in0[kc] : in1[kc - 4], a);
            if (!(kc & 1)) {
                const int g = kc >> 1;
                P0[g] = tanh2pk(src[4 * g + 0], src[4 * g + 1]);
                P1[g] = tanh2pk(src[4 * g + 2], src[4 * g + 3]);
            }
        }
    };
    // tile-tt MFMAs interleaved with the final dot of src tile tts
    auto inter8f = [&](f32x16& a, const char* wimg, int tt,
                       const f16x8* in0, const f16x8* in1,
                       const f32x16& src, int tts, float& s) {
#pragma unroll
        for (int kc = 0; kc < 8; ++kc) {
            const f16x8 av = *reinterpret_cast<const f16x8*>(
                wimg + (tt * 8 + kc) * 1024 + lane * 16);
            a = MFMA(av, kc < 4 ? in0[kc] : in1[kc - 4], a);
            if (!(kc & 1)) {
                const int g = kc >> 1;
                const f32x4v wv = *reinterpret_cast<const f32x4v*>(
                    sL + LDS_WL + (tts * 32 + g * 8) * 4 + khalf * 16);
#pragma unroll
                for (int q = 0; q < 4; ++q) {
                    const float z = src[4 * g + q];
                    const float e = __builtin_amdgcn_exp2f(z);
                    const float y = __builtin_fmaf(
                        __builtin_amdgcn_rcpf(1.0f + e), -2.0f, 1.0f);
                    s = __builtin_fmaf(y, wv[q], s);
                }
            }
        }
    };
    auto fdot = [&](const f32x16& a, int tt, float& s) {  // serial final dot
#pragma unroll
        for (int g = 0; g < 4; ++g) {
            const f32x4v wv = *reinterpret_cast<const f32x4v*>(
                sL + LDS_WL + (tt * 32 + g * 8) * 4 + khalf * 16);
#pragma unroll
            for (int q = 0; q < 4; ++q) {
                const float z = a[4 * g + q];
                const float e = __builtin_amdgcn_exp2f(z);
                const float y = __builtin_fmaf(
                    __builtin_amdgcn_rcpf(1.0f + e), -2.0f, 1.0f);
                s = __builtin_fmaf(y, wv[q], s);
            }
        }
    };

    // ------------------------ layer 0 (group-wise, 32-AGPR live) ----------
    f16x8 FA[4], FB[4], FC[4];
    {
        const char* w0i = ws + WS_W0 + (size_t)t * 8192;
        const int ro = r31 * 32 + khalf * 16;
        const int xrow = (xt * 512 + w * 32) * 32;
        const f16x8 B0h = *reinterpret_cast<const f16x8*>(ws + WS_X   + xrow + ro);
        const f16x8 B0l = *reinterpret_cast<const f16x8*>(ws + WS_XLO + xrow + ro);
        auto l0tile = [&](f32x16& a, int tt) {
#pragma unroll
            for (int g = 0; g < 4; ++g) {
                const f32x4v bv = *reinterpret_cast<const f32x4v*>(
                    wsc + tt * 32 + g * 8 + khalf * 4);
                a[4 * g + 0] = bv[0]; a[4 * g + 1] = bv[1];
                a[4 * g + 2] = bv[2]; a[4 * g + 3] = bv[3];
            }
            const f16x8 Ah = *reinterpret_cast<const f16x8*>(w0i + tt * 1024 + ro);
            const f16x8 Al = *reinterpret_cast<const f16x8*>(w0i + 4096 + tt * 1024 + ro);
            a = MFMA(Al, B0h, a);
            a = MFMA(Ah, B0l, a);
            a = MFMA(Ah, B0h, a);
        };
        f32x16 c0, c1;
        l0tile(c0, 0); l0tile(c1, 1);
        pack2(c0, &FA[0]); pack2(c1, &FA[2]);
        l0tile(c0, 2); l0tile(c1, 3);
        pack2(c0, &FB[0]); pack2(c1, &FB[2]);
    }
    __syncthreads();   // THE ONLY BARRIER: W1..W3 + tables visible

    // ------------------------ hidden layer (pipelined groups) -------------
    auto hidden = [&](const char* wimg, const char* btab,
                      f16x8* in0, f16x8* in1, f16x8* out0) {
        f32x16 c0, c1, c2, c3;
        __builtin_amdgcn_s_setprio(1);
        biasin(c0, btab, 0); mfma8(c0, wimg, 0, in0, in1);
        biasin(c1, btab, 1); mfma8(c1, wimg, 1, in0, in1);
        {
            unsigned P0[4], P1[4];
            biasin(c2, btab, 2);
            inter8(c2, wimg, 2, in0, in1, c0, P0, P1);   // pack(c0) ∥ MFMA(c2)
            asm2(P0, P1, out0 + 0);                      // kc0,1
        }
        {
            unsigned P0[4], P1[4];
            biasin(c3, btab, 3);
            inter8(c3, wimg, 3, in0, in1, c1, P0, P1);   // pack(c1) ∥ MFMA(c3)
            asm2(P0, P1, out0 + 2);                      // kc2,3
        }
        __builtin_amdgcn_s_setprio(0);
        pack2(c2, in1 + 0);                              // kc4,5 (in1 dead)
        pack2(c3, in1 + 2);                              // kc6,7
    };

    hidden(sL,         sL + LDS_B,       FA, FB, FC);   // L1: in(FA,FB)->out(FC,FB)
    hidden(sL + 32768, sL + LDS_B + 512, FC, FB, FA);   // L2: in(FC,FB)->out(FA,FB)

    // ------------------------ final layer (pipelined) ---------------------
    float s = 0.0f;
    {
        const char* wimg = sL + 65536;
        const char* btab = sL + LDS_B + 1024;
        f32x16 c0, c1, c2, c3;
        __builtin_amdgcn_s_setprio(1);
        biasin(c0, btab, 0); mfma8(c0, wimg, 0, FA, FB);
        biasin(c1, btab, 1); mfma8(c1, wimg, 1, FA, FB);
        biasin(c2, btab, 2); inter8f(c2, wimg, 2, FA, FB, c0, 0, s);
        biasin(c3, btab, 3); inter8f(c3, wimg, 3, FA, FB, c1, 1, s);
        __builtin_amdgcn_s_setprio(0);
        fdot(c2, 2, s);
        fdot(c3, 3, s);
    }
    const float sp = __builtin_bit_cast(float,
        __builtin_amdgcn_ds_bpermute(bpa, __builtin_bit_cast(int, s)));
    const float res = s + sp + *reinterpret_cast<const float*>(sL + LDS_WL + 512);
    if (!khalf) out[(size_t)t * 4096 + xt * 512 + w * 32 + r31] = res;
}

// ---------------------------------------------------------------------------
// Fallback (self-contained, known-good round-1 kernel) if ws is too small.
// ---------------------------------------------------------------------------
__global__ __launch_bounds__(256, 1)
void mlp_kernel_fb(const float* __restrict__ xin,
                   const float* __restrict__ theta,
                   float* __restrict__ out)
{
    __shared__ __align__(16) _Float16 sH   [128 * 128];
    __shared__ __align__(16) _Float16 sWhi [128 * 128];
    __shared__ __align__(16) _Float16 sWlo [128 * 128];
    __shared__ __align__(16) _Float16 sX0hi[128 * IND];
    __shared__ __align__(16) _Float16 sX0lo[128 * IND];
    __shared__ __align__(16) _Float16 sW0hi[128 * IND];
    __shared__ __align__(16) _Float16 sW0lo[128 * IND];
    __shared__ float sB[2][128];
    __shared__ float sWl[129];

    const int tid = threadIdx.x;
    const int bid = blockIdx.x;
    const int sw  = (bid & 7) * 512 + (bid >> 3);
    const int t   = sw >> 5;
    const int xt  = sw & 31;
    const float* __restrict__ th = theta + (size_t)t * PARAMS;
    const float* __restrict__ xg = xin   + (size_t)xt * (128 * IND);

#pragma unroll
    for (int j = 0; j < 2; ++j) {
        const int flat = j * 1024 + tid * 4;
        const float4 v = *reinterpret_cast<const float4*>(xg + flat);
        _Float16 h0 = (_Float16)v.x, h1 = (_Float16)v.y, h2 = (_Float16)v.z, h3 = (_Float16)v.w;
        f16x4 ph = {h0, h1, h2, h3};
        f16x4 pl = {(_Float16)(v.x - (float)h0), (_Float16)(v.y - (float)h1),
                    (_Float16)(v.z - (float)h2), (_Float16)(v.w - (float)h3)};
        *reinterpret_cast<f16x4*>(&sX0hi[flat]) = ph;
        *reinterpret_cast<f16x4*>(&sX0lo[flat]) = pl;
    }
#pragma unroll
    for (int j = 0; j < 2; ++j) {
        const int flat = j * 1024 + tid * 4;
        const float a0 = th[flat], a1 = th[flat + 1], a2 = th[flat + 2], a3 = th[flat + 3];
        _Float16 h0 = (_Float16)a0, h1 = (_Float16)a1, h2 = (_Float16)a2, h3 = (_Float16)a3;
        f16x4 ph = {h0, h1, h2, h3};
        f16x4 pl = {(_Float16)(a0 - (float)h0), (_Float16)(a1 - (float)h1),
                    (_Float16)(a2 - (float)h2), (_Float16)(a3 - (float)h3)};
        *reinterpret_cast<f16x4*>(&sW0hi[flat]) = ph;
        *reinterpret_cast<f16x4*>(&sW0lo[flat]) = pl;
    }
    if (tid < 128) sB[0][tid] = th[IND * 128 + tid];
    __syncthreads();

    const int lane  = tid & 63;
    const int w     = tid >> 6;
    const int r31   = lane & 31;
    const int khalf = lane >> 5;
    const int hb    = (w >> 1) * 64;
    const int xb    = (w & 1) * 64;
    const int hA0 = hb + r31,  hA1 = hb + 32 + r31;
    const int xB0 = xb + r31,  xB1 = xb + 32 + r31;
    const int swzA0 = (hA0 & 15) << 4, swzA1 = (hA1 & 15) << 4;
    const int swzB0 = (xB0 & 15) << 4, swzB1 = (xB1 & 15) << 4;

    f32x16 acc[2][2];

    {
        const int kb = khalf * 16;
        f16x8 ah[2], al[2], bh[2], bl[2];
        ah[0] = *reinterpret_cast<const f16x8*>((const char*)sW0hi + hA0 * 32 + kb);
        ah[1] = *reinterpret_cast<const f16x8*>((const char*)sW0hi + hA1 * 32 + kb);
        al[0] = *reinterpret_cast<const f16x8*>((const char*)sW0lo + hA0 * 32 + kb);
        al[1] = *reinterpret_cast<const f16x8*>((const char*)sW0lo + hA1 * 32 + kb);
        bh[0] = *reinterpret_cast<const f16x8*>((const char*)sX0hi + xB0 * 32 + kb);
        bh[1] = *reinterpret_cast<const f16x8*>((const char*)sX0hi + xB1 * 32 + kb);
        bl[0] = *reinterpret_cast<const f16x8*>((const char*)sX0lo + xB0 * 32 + kb);
        bl[1] = *reinterpret_cast<const f16x8*>((const char*)sX0lo + xB1 * 32 + kb);
#pragma unroll
        for (int tt = 0; tt < 2; ++tt)
#pragma unroll
            for (int tx = 0; tx < 2; ++tx) {
                f32x16 a;
#pragma unroll
                for (int i = 0; i < 16; ++i) a[i] = 0.0f;
                a = MFMA(al[tt], bh[tx], a);
                a = MFMA(ah[tt], bl[tx], a);
                a = MFMA(ah[tt], bh[tx], a);
                acc[tt][tx] = a;
            }
    }

    auto epilogue = [&](const float* __restrict__ bb) {
#pragma unroll
        for (int tt = 0; tt < 2; ++tt)
#pragma unroll
            for (int tx = 0; tx < 2; ++tx) {
                const int xw  = xb + tx * 32 + r31;
                const int swz = (xw & 15) << 4;
#pragma unroll
                for (int g = 0; g < 4; ++g) {
                    const int hbase = hb + tt * 32 + g * 8 + khalf * 4;
                    f16x4 pk;
#pragma unroll
                    for (int q = 0; q < 4; ++q) {
                        const float v = acc[tt][tx][g * 4 + q] + bb[hbase + q];
                        pk[q] = (_Float16)(1.0f - 2.0f * __builtin_amdgcn_rcpf(
                            __builtin_amdgcn_exp2f(v * 2.8853900817779268f) + 1.0f));
                    }
                    *reinterpret_cast<f16x4*>((char*)sH + xw * 256 + ((hbase * 2) ^ swz)) = pk;
                }
            }
    };

    for (int l = 0; l < 3; ++l) {
        __syncthreads();
        const float* __restrict__ wsrc = th + 2176 + l * 16512;
#pragma unroll
        for (int j = 0; j < 16; ++j) {
            const int flat = j * 1024 + tid * 4;
            const int hrow = flat >> 7;
            const int o    = flat & 127;
            const float a0 = wsrc[flat], a1 = wsrc[flat + 1], a2 = wsrc[flat + 2], a3 = wsrc[flat + 3];
            _Float16 h0 = (_Float16)a0, h1 = (_Float16)a1, h2 = (_Float16)a2, h3 = (_Float16)a3;
            f16x4 ph = {h0, h1, h2, h3};
            f16x4 pl = {(_Float16)(a0 - (float)h0), (_Float16)(a1 - (float)h1),
                        (_Float16)(a2 - (float)h2), (_Float16)(a3 - (float)h3)};
            const int boff = hrow * 256 + ((o * 2) ^ ((hrow & 15) << 4));
            *reinterpret_cast<f16x4*>((char*)sWhi + boff) = ph;
            *reinterpret_cast<f16x4*>((char*)sWlo + boff) = pl;
        }
        if (tid < 128) sB[(l + 1) & 1][tid] = wsrc[128 * 128 + tid];
        if (l == 2) {
            if (tid < 128) sWl[tid] = th[51712 + tid];
            if (tid == 128) sWl[128] = th[51840];
        }

        epilogue(sB[l & 1]);
        __syncthreads();

#pragma unroll
        for (int tt = 0; tt < 2; ++tt)
#pragma unroll
            for (int tx = 0; tx < 2; ++tx)
#pragma unroll
                for (int i = 0; i < 16; ++i) acc[tt][tx][i] = 0.0f;
#pragma unroll
        for (int kc = 0; kc < 8; ++kc) {
            const int kb = kc * 32 + khalf * 16;
            f16x8 ah[2], al[2], bv[2];
            ah[0] = *reinterpret_cast<const f16x8*>((const char*)sWhi + hA0 * 256 + (kb ^ swzA0));
            ah[1] = *reinterpret_cast<const f16x8*>((const char*)sWhi + hA1 * 256 + (kb ^ swzA1));
            al[0] = *reinterpret_cast<const f16x8*>((const char*)sWlo + hA0 * 256 + (kb ^ swzA0));
            al[1] = *reinterpret_cast<const f16x8*>((const char*)sWlo + hA1 * 256 + (kb ^ swzA1));
            bv[0] = *reinterpret_cast<const f16x8*>((const char*)sH   + xB0 * 256 + (kb ^ swzB0));
            bv[1] = *reinterpret_cast<const f16x8*>((const char*)sH   + xB1 * 256 + (kb ^ swzB1));
#pragma unroll
            for (int tt = 0; tt < 2; ++tt)
#pragma unroll
                for (int tx = 0; tx < 2; ++tx) {
                    acc[tt][tx] = MFMA(al[tt], bv[tx], acc[tt][tx]);
                    acc[tt][tx] = MFMA(ah[tt], bv[tx], acc[tt][tx]);
                }
        }
    }

    __syncthreads();
    epilogue(sB[1]);
    __syncthreads();

    if (tid < 128) {
        const int r   = tid;
        const int swz = (r & 15) << 4;
        float s = 0.0f;
#pragma unroll
        for (int c = 0; c < 16; ++c) {
            const int hc = (c + r) & 15;
            const f16x8 hv = *reinterpret_cast<const f16x8*>(
                (const char*)sH + r * 256 + ((hc * 16) ^ swz));
#pragma unroll
            for (int q = 0; q < 8; ++q) s += (float)hv[q] * sWl[hc * 8 + q];
        }
        out[(size_t)t * 4096 + (size_t)xt * 128 + r] = s + sWl[128];
    }
}

extern "C" void kernel_launch(void* const* d_in, const int* in_sizes, int n_in,
                              void* d_out, int out_size, void* d_ws, size_t ws_size,
                              hipStream_t stream)
{
    const float* x     = (const float*)d_in[0];
    const float* theta = (const float*)d_in[1];
    float* out = (float*)d_out;

    if (ws_size >= (size_t)WS_TOTAL) {
        prep_kernel<<<dim3(3280), dim3(256), 0, stream>>>(theta, x, (char*)d_ws);
        mlp_main<<<dim3(1024), dim3(THREADS), 0, stream>>>((const char*)d_ws, out);
    } else {
        mlp_kernel_fb<<<dim3(4096), dim3(256), 0, stream>>>(x, theta, out);
    }
}